// Round 6
// baseline (260.145 us; speedup 1.0000x reference)
//
#include <hip/hip_runtime.h>
#include <hip/hip_fp16.h>
#include <cstdint>
#include <cstddef>

#define TPB 256
#define CAP 64     // slots per node (Poisson(16) tail: P(deg>64) ~ 3e-20)
#define FWSHIFT 9  // fill-window = 512 nodes (LDS cursor array 2KB)
#define FWROWS 512
#define CAPB 96    // per-(window,decode-block) bucket capacity.
                   // lambda = 8192*512/100000 = 42; P(Poisson(42)>=96) ~ 1e-11.
#define DEC_ITERS 32  // edges per decode thread; 8192/block

// r16: atomic-free CSR build (bucket by dst window at decode; fill block owns
//      a window) killed the 88us global-atomic floor: 288->258us.
// r17: 8-deep gather unroll REGRESSED (occ 65->38): gathers sit at a ~3.4TB/s
//      fabric ceiling (each XCD re-fetches whole 25.6MB xw1: 8x25.6 ~= 199MB
//      FETCH; structural for dst-gather on a random graph).
// r18: lsm 8 lanes x 16B (half the requests, same bytes) -8.5us total ->
//      plateau has a request-rate component at equal bytes.
// r19: (a) buckets packed to 32b (dstLocal:9|src:17) — halves decode-write /
//      fill-read traffic. (b) re-pair overlap: k1={W2,decode}, k2={fill ||
//      gemm1} (fill hidden under gemm1 instead of running serial).
//      (c) nontemporal slot loads in gathers (read-once stream was evicting
//      xw1/xw2 from L2).

using half8 = __attribute__((ext_vector_type(8))) _Float16;
using f32x4 = __attribute__((ext_vector_type(4))) float;
using i32x4 = __attribute__((ext_vector_type(4))) int;

struct GemmSm {
    _Float16 Wl[32 * 64 * 8];          // 32 KB: W1 in MFMA B-frag order
    _Float16 Of[4][16 * 136];          // 17 KB: per-wave output staging
};
struct FillSm { int cur[FWROWS]; };
union MegaSm { GemmSm g; FillSm f; };  // 50176 B -> 3 blocks/CU

// ---------------------------------------------------------------------------
// K1 (one dispatch, small LDS, high occupancy):
//  blocks [0,8):    W2 fp32 -> fp16 MFMA B-frag order in global wf2 (16 KB)
//  blocks [8,...):  decode edge_index + bucket by 512-node dst window:
//                   bpack[fw][dblk][pos] = (dstLocal<<17)|src (32-bit).
//                   Per-block dtype self-detection from first 256 int64s.
// ---------------------------------------------------------------------------
__global__ __launch_bounds__(256)
void k_setup(const void* __restrict__ ei, int E, int N,
             const float* __restrict__ W2, _Float16* __restrict__ wf2,
             int* __restrict__ bpack, int* __restrict__ bcnt,
             int nDec, int nFW) {
    const int b = blockIdx.x;
    const int tid = threadIdx.x;

    if (b < 8) {
        int i = b * TPB + tid;                           // 0..2047
        int k  = i >> 4;
        int n0 = (i & 15) * 4;
        float4 w = ((const float4*)W2)[i];
        int ct = n0 >> 4, kb = k >> 5;
        int lane0 = ((k >> 3) & 3) * 16 + (n0 & 15);
        int j = k & 7;
        int base = ((ct * 4 + kb) * 64 + lane0) * 8 + j;
        wf2[base]      = (_Float16)w.x;
        wf2[base + 8]  = (_Float16)w.y;
        wf2[base + 16] = (_Float16)w.z;
        wf2[base + 24] = (_Float16)w.w;
    } else {
        // ---- decode + bucket (packed 32-bit) ----
        __shared__ int cur[256];                 // nFW <= 256 cursors
        __shared__ int bad;
        const int dblk = b - 8;
        if (tid == 0) bad = 0;
        for (int f = tid; f < nFW; f += TPB) cur[f] = 0;
        __syncthreads();
        {
            long long v = ((const long long*)ei)[tid];
            if (v < 0 || v >= (long long)N) bad = 1;
        }
        __syncthreads();
        const int is64 = !bad;
        const int base = dblk * (TPB * DEC_ITERS);
        const long long* e64 = (const long long*)ei;
        const int* e32 = (const int*)ei;

        for (int it = 0; it < DEC_ITERS; it += 4) {
            int d[4], s[4]; bool val[4];
#pragma unroll
            for (int k = 0; k < 4; ++k) {
                int e = base + (it + k) * TPB + tid;
                val[k] = e < E;
                if (val[k]) {
                    if (is64) { d[k] = (int)e64[e]; s[k] = (int)e64[(long long)E + e]; }
                    else      { d[k] = e32[e];      s[k] = e32[E + e]; }
                }
            }
#pragma unroll
            for (int k = 0; k < 4; ++k) {
                if (val[k]) {
                    int fw  = d[k] >> FWSHIFT;
                    int pos = atomicAdd(&cur[fw], 1);     // LDS atomic
                    if (pos < CAPB)
                        bpack[((size_t)fw * nDec + dblk) * CAPB + pos] =
                            ((d[k] & (FWROWS - 1)) << 17) | s[k];
                }
            }
        }
        __syncthreads();
        for (int f = tid; f < nFW; f += TPB) {
            int c = cur[f];
            bcnt[(size_t)f * nDec + dblk] = c > CAPB ? CAPB : c;
        }
    }
}

// ---------------------------------------------------------------------------
// K2 MEGA: fill || gemm1 (fill depends on decode; gemm1 independent — their
// durations are matched, so fill hides under gemm1's streaming phase).
//  blocks [0,nFW):       atomic-free fill: block owns window fw; LDS cursors.
//  blocks [nFW,nFW+512): gemm1 (x @ W1 -> xw1 fp16, unscaled); W1 self-
//                        converted into LDS per block (L2-hot 64 KB read).
// ---------------------------------------------------------------------------
__global__ __launch_bounds__(256)
void k_mega(const int* __restrict__ bpack, const int* __restrict__ bcnt,
            int nDec, int N,
            int* __restrict__ cnt, float* __restrict__ dinv,
            int* __restrict__ slots,
            const float* __restrict__ x, const float* __restrict__ W1,
            __half* __restrict__ xw1, int nFW, int nGemm) {
    __shared__ __align__(16) MegaSm sm;
    const int tid = threadIdx.x;

    if ((int)blockIdx.x < nFW) {
        // ---------------- fill path: window fw, zero global atomics --------
        const int fw = blockIdx.x;
        const int lo = fw << FWSHIFT;
        for (int i = tid; i < FWROWS; i += TPB) sm.f.cur[i] = 0;
        __syncthreads();

        for (int s = tid; s < nDec; s += TPB) {
            const int c = bcnt[(size_t)fw * nDec + s];
            const int* bp = bpack + ((size_t)fw * nDec + s) * CAPB;
            int j = 0;
            for (; j + 3 < c; j += 4) {
                i32x4 u = __builtin_nontemporal_load((const i32x4*)(bp + j));
                int dl0 = u[0] >> 17, s0 = u[0] & 0x1FFFF;
                int dl1 = u[1] >> 17, s1 = u[1] & 0x1FFFF;
                int dl2 = u[2] >> 17, s2 = u[2] & 0x1FFFF;
                int dl3 = u[3] >> 17, s3 = u[3] & 0x1FFFF;
                int q0 = atomicAdd(&sm.f.cur[dl0], 1);
                int q1 = atomicAdd(&sm.f.cur[dl1], 1);
                int q2 = atomicAdd(&sm.f.cur[dl2], 1);
                int q3 = atomicAdd(&sm.f.cur[dl3], 1);
                if (q0 < CAP) slots[(size_t)(lo + dl0) * CAP + q0] = s0;
                if (q1 < CAP) slots[(size_t)(lo + dl1) * CAP + q1] = s1;
                if (q2 < CAP) slots[(size_t)(lo + dl2) * CAP + q2] = s2;
                if (q3 < CAP) slots[(size_t)(lo + dl3) * CAP + q3] = s3;
            }
            for (; j < c; ++j) {
                int v = __builtin_nontemporal_load(bp + j);
                int dl = v >> 17, sv = v & 0x1FFFF;
                int pos = atomicAdd(&sm.f.cur[dl], 1);
                if (pos < CAP) slots[(size_t)(lo + dl) * CAP + pos] = sv;
            }
        }
        __syncthreads();
        for (int i = tid; i < FWROWS; i += TPB) {
            int node = lo + i;
            if (node < N) {
                int cc = sm.f.cur[i];
                cnt[node]  = cc;
                dinv[node] = rsqrtf((float)cc + 1.0f);
            }
        }
    } else {
        // ---------------- gemm1 path (unscaled): W1 -> LDS, x @ W1 --------
        const int gb = (int)blockIdx.x - nFW;
        for (int i = tid; i < 4096; i += TPB) {
            float4 w = ((const float4*)W1)[i];
            int k  = i >> 5;
            int n0 = (i & 31) * 4;
            int ct = n0 >> 4, kb = k >> 5;
            int lane0 = ((k >> 3) & 3) * 16 + (n0 & 15);
            int j = k & 7;
            int bs = ((ct * 4 + kb) * 64 + lane0) * 8 + j;
            sm.g.Wl[bs]      = (_Float16)w.x;
            sm.g.Wl[bs + 8]  = (_Float16)w.y;
            sm.g.Wl[bs + 16] = (_Float16)w.z;
            sm.g.Wl[bs + 24] = (_Float16)w.w;
        }
        __syncthreads();
        const half8* wl = (const half8*)sm.g.Wl;
        const int wave = tid >> 6, lane = tid & 63;
        const int m = lane & 15, quad = lane >> 4;
        const int nRowTiles = (N + 15) >> 4;

        for (int rt = gb * 4 + wave; rt < nRowTiles; rt += nGemm * 4) {
            const int row0 = rt * 16;
            const int arow = row0 + m;
            const bool rvalid = arow < N;
            const float* xrow = x + (size_t)(rvalid ? arow : 0) * 128;

            f32x4 acc[8];
#pragma unroll
            for (int ct = 0; ct < 8; ++ct) acc[ct] = (f32x4){0.f, 0.f, 0.f, 0.f};

#pragma unroll
            for (int kb = 0; kb < 4; ++kb) {
                const float4* ap = (const float4*)(xrow + kb * 32 + quad * 8);
                float4 a0 = ap[0], a1 = ap[1];
                half8 a;
                a[0] = (_Float16)a0.x; a[1] = (_Float16)a0.y;
                a[2] = (_Float16)a0.z; a[3] = (_Float16)a0.w;
                a[4] = (_Float16)a1.x; a[5] = (_Float16)a1.y;
                a[6] = (_Float16)a1.z; a[7] = (_Float16)a1.w;
#pragma unroll
                for (int ct = 0; ct < 8; ++ct) {
                    half8 bfr = wl[(ct * 4 + kb) * 64 + lane];
                    acc[ct] = __builtin_amdgcn_mfma_f32_16x16x32_f16(a, bfr, acc[ct], 0, 0, 0);
                }
            }

            _Float16* myO = &sm.g.Of[wave][0];
#pragma unroll
            for (int ct = 0; ct < 8; ++ct)
#pragma unroll
                for (int r = 0; r < 4; ++r)
                    myO[(quad * 4 + r) * 136 + ct * 16 + m] = (_Float16)acc[ct][r];
            int vr = N - row0; if (vr > 16) vr = 16;
            float4* dst = (float4*)(xw1 + (size_t)row0 * 128);
            for (int i = lane; i < vr * 16; i += 64) {
                int r = i >> 4, q = i & 15;
                dst[r * 16 + q] = *(const float4*)&myO[r * 136 + q * 8];
            }
        }
    }
}

// ---------------------------------------------------------------------------
// FUSED gather1 + gemm2 (4-edge unroll — 8-deep REGRESSED, r17).
// Epilogue PRE-SCALES xw2 rows by dinv[node]. Per-edge norm from packed
// dinv[] table. r19: slot loads nontemporal (protect xw1 L2 residency).
// ---------------------------------------------------------------------------
__global__ __launch_bounds__(256)
void k_g1g2(const __half* __restrict__ xw1, const int* __restrict__ cnt,
            const float* __restrict__ dinv,
            const int* __restrict__ slots, const float* __restrict__ bias,
            const half8* __restrict__ wf2, __half* __restrict__ xw2, int N) {
    __shared__ __align__(16) _Float16 Ht[16 * 136];   // h tile, padded
    __shared__ __align__(16) _Float16 Of[16 * 72];    // xw2 transpose
    __shared__ float dv16[16];                        // dinv per tile row

    const int row0 = blockIdx.x * 16;
    const int local = threadIdx.x >> 4;     // 0..15: node within tile
    const int lane16 = threadIdx.x & 15;    // feature quad: 8 halves
    const int node = row0 + local;

    // ---- phase 1: gather ----
    {
        union { __half2 h2[4]; float4 f; } u;
        float dvn = 0.f;
        if (node < N) {
            int cn = cnt[node];
            int len = cn > CAP ? CAP : cn;
            dvn = dinv[node];
            const int* sl = slots + (size_t)node * CAP;
            float acc[8];
            {
                float4 raw = *(const float4*)(xw1 + (size_t)node * 128 + lane16 * 8);
                const __half2* hp = (const __half2*)&raw;
#pragma unroll
                for (int k = 0; k < 4; ++k) {
                    float2 f = __half22float2(hp[k]);
                    acc[2 * k] = dvn * f.x; acc[2 * k + 1] = dvn * f.y;
                }
            }
            int j = 0;
            for (; j + 3 < len; j += 4) {
                i32x4 cc = __builtin_nontemporal_load((const i32x4*)(sl + j));
                float dv0 = dinv[cc[0]];
                float dv1 = dinv[cc[1]];
                float dv2 = dinv[cc[2]];
                float dv3 = dinv[cc[3]];
                float4 raw0 = *(const float4*)(xw1 + (size_t)cc[0] * 128 + lane16 * 8);
                float4 raw1 = *(const float4*)(xw1 + (size_t)cc[1] * 128 + lane16 * 8);
                float4 raw2 = *(const float4*)(xw1 + (size_t)cc[2] * 128 + lane16 * 8);
                float4 raw3 = *(const float4*)(xw1 + (size_t)cc[3] * 128 + lane16 * 8);
                const __half2* h0 = (const __half2*)&raw0;
                const __half2* h1 = (const __half2*)&raw1;
                const __half2* h2 = (const __half2*)&raw2;
                const __half2* h3 = (const __half2*)&raw3;
#pragma unroll
                for (int k = 0; k < 4; ++k) {
                    float2 f0 = __half22float2(h0[k]);
                    float2 f1 = __half22float2(h1[k]);
                    float2 f2 = __half22float2(h2[k]);
                    float2 f3 = __half22float2(h3[k]);
                    acc[2 * k]     = fmaf(dv0, f0.x, fmaf(dv1, f1.x,
                                     fmaf(dv2, f2.x, fmaf(dv3, f3.x, acc[2 * k]))));
                    acc[2 * k + 1] = fmaf(dv0, f0.y, fmaf(dv1, f1.y,
                                     fmaf(dv2, f2.y, fmaf(dv3, f3.y, acc[2 * k + 1]))));
                }
            }
            for (; j < len; ++j) {
                int c = __builtin_nontemporal_load(sl + j);
                float dv = dinv[c];
                float4 raw = *(const float4*)(xw1 + (size_t)c * 128 + lane16 * 8);
                const __half2* hp = (const __half2*)&raw;
#pragma unroll
                for (int k = 0; k < 4; ++k) {
                    float2 f = __half22float2(hp[k]);
                    acc[2 * k]     = fmaf(dv, f.x, acc[2 * k]);
                    acc[2 * k + 1] = fmaf(dv, f.y, acc[2 * k + 1]);
                }
            }
            float4 b01 = ((const float4*)bias)[lane16 * 2];
            float4 b23 = ((const float4*)bias)[lane16 * 2 + 1];
            float v[8];
            v[0] = b01.x + dvn * acc[0]; v[1] = b01.y + dvn * acc[1];
            v[2] = b01.z + dvn * acc[2]; v[3] = b01.w + dvn * acc[3];
            v[4] = b23.x + dvn * acc[4]; v[5] = b23.y + dvn * acc[5];
            v[6] = b23.z + dvn * acc[6]; v[7] = b23.w + dvn * acc[7];
#pragma unroll
            for (int k = 0; k < 4; ++k)
                u.h2[k] = __floats2half2_rn(fmaxf(v[2 * k], 0.f), fmaxf(v[2 * k + 1], 0.f));
        } else {
            u.f = make_float4(0.f, 0.f, 0.f, 0.f);
        }
        if (lane16 == 0) dv16[local] = dvn;
        *(float4*)(Ht + local * 136 + lane16 * 8) = u.f;
    }
    __syncthreads();

    // ---- phase 2: MFMA h_tile @ W2, wave ct; scale rows by dinv[node] ----
    {
        const int wave = threadIdx.x >> 6, lane = threadIdx.x & 63;
        const int m = lane & 15, quad = lane >> 4;
        f32x4 acc = (f32x4){0.f, 0.f, 0.f, 0.f};
#pragma unroll
        for (int kb = 0; kb < 4; ++kb) {
            half8 a = *(const half8*)(Ht + m * 136 + kb * 32 + quad * 8);
            half8 b = wf2[(wave * 4 + kb) * 64 + lane];
            acc = __builtin_amdgcn_mfma_f32_16x16x32_f16(a, b, acc, 0, 0, 0);
        }
#pragma unroll
        for (int r = 0; r < 4; ++r)
            Of[(quad * 4 + r) * 72 + wave * 16 + m] =
                (_Float16)(acc[r] * dv16[quad * 4 + r]);
    }
    __syncthreads();
    {
        int vr = N - row0; if (vr > 16) vr = 16;
        float4* dst = (float4*)(xw2 + (size_t)row0 * 64);
        for (int i = threadIdx.x; i < vr * 8; i += TPB) {
            int r = i >> 3, q = i & 7;
            dst[r * 8 + q] = *(const float4*)&Of[r * 72 + q * 8];
        }
    }
}

// ---------------------------------------------------------------------------
// Capacity-CSR gather, layer 2 (F=64, fp16 src PRE-SCALED by dinv[src]),
// FUSED bias + self-loop + norm + log_softmax.
// r18: 8 lanes/node x 16B. r19: nontemporal slot loads.
// ---------------------------------------------------------------------------
__global__ void k_gather2_lsm(const __half* __restrict__ xws, const int* __restrict__ cnt,
                              const float* __restrict__ dinv,
                              const int* __restrict__ slots,
                              const float* __restrict__ bias, float* __restrict__ out, int N) {
    long long t = (long long)blockIdx.x * TPB + threadIdx.x;
    int node = (int)(t >> 3);
    int lane = (int)(t & 7);              // 8 features (16B fp16) per lane
    if (node >= N) return;
    int cn = cnt[node];
    int len = cn > CAP ? CAP : cn;
    float dvn = dinv[node];
    const int* sl = slots + (size_t)node * CAP;
    float a[8];
    {
        // self term: stored row is dvn*h2[n]; final *dvn gives dvn^2*h2[n].
        float4 raw = *(const float4*)(xws + (size_t)node * 64 + lane * 8);
        const __half2* hp = (const __half2*)&raw;
#pragma unroll
        for (int k = 0; k < 4; ++k) {
            float2 f = __half22float2(hp[k]);
            a[2 * k] = f.x; a[2 * k + 1] = f.y;
        }
    }
    int j = 0;
    for (; j + 3 < len; j += 4) {
        i32x4 cc = __builtin_nontemporal_load((const i32x4*)(sl + j));
        float4 r0 = *(const float4*)(xws + (size_t)cc[0] * 64 + lane * 8);
        float4 r1 = *(const float4*)(xws + (size_t)cc[1] * 64 + lane * 8);
        float4 r2 = *(const float4*)(xws + (size_t)cc[2] * 64 + lane * 8);
        float4 r3 = *(const float4*)(xws + (size_t)cc[3] * 64 + lane * 8);
        const __half2* h0 = (const __half2*)&r0;
        const __half2* h1 = (const __half2*)&r1;
        const __half2* h2 = (const __half2*)&r2;
        const __half2* h3 = (const __half2*)&r3;
#pragma unroll
        for (int k = 0; k < 4; ++k) {
            float2 f0 = __half22float2(h0[k]);
            float2 f1 = __half22float2(h1[k]);
            float2 f2 = __half22float2(h2[k]);
            float2 f3 = __half22float2(h3[k]);
            a[2 * k]     += (f0.x + f1.x) + (f2.x + f3.x);
            a[2 * k + 1] += (f0.y + f1.y) + (f2.y + f3.y);
        }
    }
    for (; j < len; ++j) {
        int c = __builtin_nontemporal_load(sl + j);
        float4 raw = *(const float4*)(xws + (size_t)c * 64 + lane * 8);
        const __half2* hp = (const __half2*)&raw;
#pragma unroll
        for (int k = 0; k < 4; ++k) {
            float2 f = __half22float2(hp[k]);
            a[2 * k] += f.x; a[2 * k + 1] += f.y;
        }
    }
    float4 b01 = ((const float4*)bias)[lane * 2];
    float4 b23 = ((const float4*)bias)[lane * 2 + 1];
    float v[8];
    v[0] = b01.x + dvn * a[0]; v[1] = b01.y + dvn * a[1];
    v[2] = b01.z + dvn * a[2]; v[3] = b01.w + dvn * a[3];
    v[4] = b23.x + dvn * a[4]; v[5] = b23.y + dvn * a[5];
    v[6] = b23.z + dvn * a[6]; v[7] = b23.w + dvn * a[7];

    float m = v[0];
#pragma unroll
    for (int k = 1; k < 8; ++k) m = fmaxf(m, v[k]);
#pragma unroll
    for (int off = 1; off < 8; off <<= 1) m = fmaxf(m, __shfl_xor(m, off));
    float s = 0.f;
#pragma unroll
    for (int k = 0; k < 8; ++k) s += expf(v[k] - m);
#pragma unroll
    for (int off = 1; off < 8; off <<= 1) s += __shfl_xor(s, off);
    float ls = m + logf(s);
    float4 o0 = make_float4(v[0] - ls, v[1] - ls, v[2] - ls, v[3] - ls);
    float4 o1 = make_float4(v[4] - ls, v[5] - ls, v[6] - ls, v[7] - ls);
    ((float4*)(out + (size_t)node * 64))[lane * 2]     = o0;
    ((float4*)(out + (size_t)node * 64))[lane * 2 + 1] = o1;
}

// ---------------------------------------------------------------------------
extern "C" void kernel_launch(void* const* d_in, const int* in_sizes, int n_in,
                              void* d_out, int out_size, void* d_ws, size_t ws_size,
                              hipStream_t stream) {
    const float* x  = (const float*)d_in[0];
    const void*  ei = d_in[1];
    const float* W1 = (const float*)d_in[2];
    const float* b1 = (const float*)d_in[3];
    const float* W2 = (const float*)d_in[4];
    const float* b2 = (const float*)d_in[5];
    float* out = (float*)d_out;

    const int N = in_sizes[0] / 128;   // 100000  (must be < 2^17 for packing)
    const int E = in_sizes[1] / 2;     // 1600000

    const int nFW  = (N + FWROWS - 1) >> FWSHIFT;                   // 196
    const int nDec = (E + TPB * DEC_ITERS - 1) / (TPB * DEC_ITERS); // 196
    const int nGemm = 512;

    char* base = (char*)d_ws;
    size_t off = 0;
    auto alloc = [&](size_t bytes) { char* p = base + off; off = (off + bytes + 255) & ~(size_t)255; return p; };
    int*      cnt    = (int*)alloc((size_t)N * sizeof(int));
    float*    dinv   = (float*)alloc((size_t)N * sizeof(float));
    _Float16* wf2    = (_Float16*)alloc(128 * 64 * sizeof(_Float16));
    int*      bcnt   = (int*)alloc((size_t)nFW * nDec * sizeof(int));
    int*      bpack  = (int*)alloc((size_t)nFW * nDec * CAPB * sizeof(int)); // 14.7MB
    int*      slots  = (int*)alloc((size_t)N * CAP * sizeof(int));
    __half*   xw1    = (__half*)alloc((size_t)N * 128 * sizeof(__half));
    __half*   xw2    = (__half*)alloc((size_t)N * 64 * sizeof(__half));
    (void)ws_size;

    const int nodeTiles = (N + 15) / 16;

    k_setup<<<8 + nDec, TPB, 0, stream>>>(ei, E, N, W2, wf2, bpack, bcnt,
                                          nDec, nFW);

    k_mega<<<nFW + nGemm, TPB, 0, stream>>>(bpack, bcnt, nDec, N, cnt, dinv,
                                            slots, x, W1, xw1, nFW, nGemm);

    k_g1g2<<<nodeTiles, TPB, 0, stream>>>(xw1, cnt, dinv, slots, b1,
                                          (const half8*)wf2, xw2, N);

    {
        long long t = (long long)N * 8;
        k_gather2_lsm<<<(int)((t + TPB - 1) / TPB), TPB, 0, stream>>>(xw2, cnt, dinv, slots, b2, out, N);
    }
}

// Round 7
// 238.212 us; speedup vs baseline: 1.0921x; 1.0921x over previous
//
#include <hip/hip_runtime.h>
#include <hip/hip_fp16.h>
#include <cstdint>
#include <cstddef>

#define TPB 256
#define CAP 64     // slots per node (Poisson(16) tail: P(deg>64) ~ 3e-20)
#define FWSHIFT 9  // fill-window = 512 nodes (LDS cursor array 2KB)
#define FWROWS 512
#define DEC_ITERS 32              // edges per decode thread
#define DEC_EDGES (TPB * DEC_ITERS)  // 8192 per decode block

// r16: atomic-free CSR build (bucket by dst window at decode; fill block owns
//      a window) killed the 88us global-atomic floor: 288->258us.
// r17: 8-deep gather unroll REGRESSED: gathers sit at a ~3.4TB/s L2-miss
//      fabric ceiling (each XCD re-fetches whole 25.6MB xw1 ~= 199MB FETCH;
//      structural for dst-gather on a random graph).
// r18: lsm 8 lanes x 16B (half the requests, same bytes): -8.5us.
// r19: NT slot/bucket loads REGRESSED (+15.5us, FETCH +18.5MB): nt bypasses
//      cache so 16B-per-thread streams re-fetch each 64B line 4x. REVERTED.
// r20: decode rewritten as 3-phase block-local counting sort: edges held in
//      REGISTERS (histogram pass), LDS scan -> window bases, place into 32KB
//      LDS buffer, flush DENSE+COALESCED to bpack[dblk][8192] (+ per-window
//      base/cnt). Kills the ~100MB effective scattered-write traffic; bpack
//      14.7->6.4MB dense; no more CAPB overflow cap.

using half8 = __attribute__((ext_vector_type(8))) _Float16;
using f32x4 = __attribute__((ext_vector_type(4))) float;

struct GemmSm {
    _Float16 Wl[32 * 64 * 8];          // 32 KB: W1 in MFMA B-frag order
    _Float16 Of[4][16 * 136];          // 17 KB: per-wave output staging
};
struct FillSm { int cur[FWROWS]; };
union MegaSm { GemmSm g; FillSm f; };  // 50176 B -> 3 blocks/CU

// ---------------------------------------------------------------------------
// K1 (one dispatch):
//  blocks [0,8):    W2 fp32 -> fp16 MFMA B-frag order in global wf2 (16 KB)
//  blocks [8,...):  decode + 3-phase bucket sort by 512-node dst window.
//                   bpack[dblk][i] dense; bbase/bcnt[fw][dblk] segment map.
//                   Packed edge = (dstLocal:9 << 17) | src:17  (N < 2^17).
// ---------------------------------------------------------------------------
__global__ __launch_bounds__(256)
void k_setup(const void* __restrict__ ei, int E, int N,
             const float* __restrict__ W2, _Float16* __restrict__ wf2,
             int* __restrict__ bpack, int* __restrict__ bbase,
             int* __restrict__ bcnt, int nDec, int nFW) {
    __shared__ int buf[DEC_EDGES];     // 32 KB
    __shared__ int lcnt[256];
    __shared__ int lofs[256];
    __shared__ int sc[256];
    __shared__ int bad;
    const int b = blockIdx.x;
    const int tid = threadIdx.x;

    if (b < 8) {
        int i = b * TPB + tid;                           // 0..2047
        int k  = i >> 4;
        int n0 = (i & 15) * 4;
        float4 w = ((const float4*)W2)[i];
        int ct = n0 >> 4, kb = k >> 5;
        int lane0 = ((k >> 3) & 3) * 16 + (n0 & 15);
        int j = k & 7;
        int base = ((ct * 4 + kb) * 64 + lane0) * 8 + j;
        wf2[base]      = (_Float16)w.x;
        wf2[base + 8]  = (_Float16)w.y;
        wf2[base + 16] = (_Float16)w.z;
        wf2[base + 24] = (_Float16)w.w;
        return;
    }

    // ---- decode + 3-phase bucket sort ----
    const int dblk = b - 8;
    if (tid == 0) bad = 0;
    lcnt[tid] = 0;
    __syncthreads();
    {
        long long v = ((const long long*)ei)[tid];
        if (v < 0 || v >= (long long)N) bad = 1;
    }
    __syncthreads();
    const int is64 = !bad;
    const int base = dblk * DEC_EDGES;
    const long long* e64 = (const long long*)ei;
    const int* e32 = (const int*)ei;

    // phase 1: read edges into REGISTERS (static indices), histogram windows
    int pv[DEC_ITERS];
    int pfw[DEC_ITERS];
#pragma unroll
    for (int k = 0; k < DEC_ITERS; ++k) {
        int e = base + k * TPB + tid;
        pfw[k] = -1;
        pv[k] = 0;
        if (e < E) {
            int d, s;
            if (is64) { d = (int)e64[e]; s = (int)e64[(long long)E + e]; }
            else      { d = e32[e];      s = e32[E + e]; }
            pfw[k] = d >> FWSHIFT;
            pv[k]  = ((d & (FWROWS - 1)) << 17) | s;
            atomicAdd(&lcnt[pfw[k]], 1);
        }
    }
    __syncthreads();

    // phase 2: scan window counts -> bases; place into LDS buffer
    int c = lcnt[tid];
    sc[tid] = c;
    __syncthreads();
    for (int off = 1; off < 256; off <<= 1) {
        int v = (tid >= off) ? sc[tid - off] : 0;
        __syncthreads();
        sc[tid] += v;
        __syncthreads();
    }
    lofs[tid] = sc[tid] - c;            // exclusive base
    __syncthreads();
#pragma unroll
    for (int k = 0; k < DEC_ITERS; ++k) {
        if (pfw[k] >= 0) {
            int pos = atomicAdd(&lofs[pfw[k]], 1);
            buf[pos] = pv[k];
        }
    }
    __syncthreads();

    // phase 3: dense coalesced flush + segment map
    const int total = sc[255];
    for (int i = tid; i < total; i += TPB)
        bpack[(size_t)dblk * DEC_EDGES + i] = buf[i];
    if (tid < nFW) {
        bbase[(size_t)tid * nDec + dblk] = sc[tid] - c;
        bcnt [(size_t)tid * nDec + dblk] = c;
    }
}

// ---------------------------------------------------------------------------
// K2 MEGA: fill || gemm1.
//  blocks [0,nFW):       atomic-free fill: block owns window fw; LDS cursors.
//  blocks [nFW,nFW+512): gemm1 (x @ W1 -> xw1 fp16, unscaled); W1 self-
//                        converted into LDS per block (L2-hot 64 KB read).
// ---------------------------------------------------------------------------
__global__ __launch_bounds__(256)
void k_mega(const int* __restrict__ bpack, const int* __restrict__ bbase,
            const int* __restrict__ bcnt, int nDec, int N,
            int* __restrict__ cnt, float* __restrict__ dinv,
            int* __restrict__ slots,
            const float* __restrict__ x, const float* __restrict__ W1,
            __half* __restrict__ xw1, int nFW, int nGemm) {
    __shared__ __align__(16) MegaSm sm;
    const int tid = threadIdx.x;

    if ((int)blockIdx.x < nFW) {
        // ---------------- fill path: window fw, zero global atomics --------
        const int fw = blockIdx.x;
        const int lo = fw << FWSHIFT;
        for (int i = tid; i < FWROWS; i += TPB) sm.f.cur[i] = 0;
        __syncthreads();

        for (int s = tid; s < nDec; s += TPB) {
            const size_t seg = (size_t)fw * nDec + s;
            const int c = bcnt[seg];
            const int* bp = bpack + (size_t)s * DEC_EDGES + bbase[seg];
            int j = 0;
            for (; j + 3 < c; j += 4) {
                int v0 = bp[j], v1 = bp[j + 1], v2 = bp[j + 2], v3 = bp[j + 3];
                int dl0 = v0 >> 17, s0 = v0 & 0x1FFFF;
                int dl1 = v1 >> 17, s1 = v1 & 0x1FFFF;
                int dl2 = v2 >> 17, s2 = v2 & 0x1FFFF;
                int dl3 = v3 >> 17, s3 = v3 & 0x1FFFF;
                int q0 = atomicAdd(&sm.f.cur[dl0], 1);
                int q1 = atomicAdd(&sm.f.cur[dl1], 1);
                int q2 = atomicAdd(&sm.f.cur[dl2], 1);
                int q3 = atomicAdd(&sm.f.cur[dl3], 1);
                if (q0 < CAP) slots[(size_t)(lo + dl0) * CAP + q0] = s0;
                if (q1 < CAP) slots[(size_t)(lo + dl1) * CAP + q1] = s1;
                if (q2 < CAP) slots[(size_t)(lo + dl2) * CAP + q2] = s2;
                if (q3 < CAP) slots[(size_t)(lo + dl3) * CAP + q3] = s3;
            }
            for (; j < c; ++j) {
                int v = bp[j];
                int dl = v >> 17, sv = v & 0x1FFFF;
                int pos = atomicAdd(&sm.f.cur[dl], 1);
                if (pos < CAP) slots[(size_t)(lo + dl) * CAP + pos] = sv;
            }
        }
        __syncthreads();
        for (int i = tid; i < FWROWS; i += TPB) {
            int node = lo + i;
            if (node < N) {
                int cc = sm.f.cur[i];
                cnt[node]  = cc;
                dinv[node] = rsqrtf((float)cc + 1.0f);
            }
        }
    } else {
        // ---------------- gemm1 path (unscaled): W1 -> LDS, x @ W1 --------
        const int gb = (int)blockIdx.x - nFW;
        for (int i = tid; i < 4096; i += TPB) {
            float4 w = ((const float4*)W1)[i];
            int k  = i >> 5;
            int n0 = (i & 31) * 4;
            int ct = n0 >> 4, kb = k >> 5;
            int lane0 = ((k >> 3) & 3) * 16 + (n0 & 15);
            int j = k & 7;
            int bs = ((ct * 4 + kb) * 64 + lane0) * 8 + j;
            sm.g.Wl[bs]      = (_Float16)w.x;
            sm.g.Wl[bs + 8]  = (_Float16)w.y;
            sm.g.Wl[bs + 16] = (_Float16)w.z;
            sm.g.Wl[bs + 24] = (_Float16)w.w;
        }
        __syncthreads();
        const half8* wl = (const half8*)sm.g.Wl;
        const int wave = tid >> 6, lane = tid & 63;
        const int m = lane & 15, quad = lane >> 4;
        const int nRowTiles = (N + 15) >> 4;

        for (int rt = gb * 4 + wave; rt < nRowTiles; rt += nGemm * 4) {
            const int row0 = rt * 16;
            const int arow = row0 + m;
            const bool rvalid = arow < N;
            const float* xrow = x + (size_t)(rvalid ? arow : 0) * 128;

            f32x4 acc[8];
#pragma unroll
            for (int ct = 0; ct < 8; ++ct) acc[ct] = (f32x4){0.f, 0.f, 0.f, 0.f};

#pragma unroll
            for (int kb = 0; kb < 4; ++kb) {
                const float4* ap = (const float4*)(xrow + kb * 32 + quad * 8);
                float4 a0 = ap[0], a1 = ap[1];
                half8 a;
                a[0] = (_Float16)a0.x; a[1] = (_Float16)a0.y;
                a[2] = (_Float16)a0.z; a[3] = (_Float16)a0.w;
                a[4] = (_Float16)a1.x; a[5] = (_Float16)a1.y;
                a[6] = (_Float16)a1.z; a[7] = (_Float16)a1.w;
#pragma unroll
                for (int ct = 0; ct < 8; ++ct) {
                    half8 bfr = wl[(ct * 4 + kb) * 64 + lane];
                    acc[ct] = __builtin_amdgcn_mfma_f32_16x16x32_f16(a, bfr, acc[ct], 0, 0, 0);
                }
            }

            _Float16* myO = &sm.g.Of[wave][0];
#pragma unroll
            for (int ct = 0; ct < 8; ++ct)
#pragma unroll
                for (int r = 0; r < 4; ++r)
                    myO[(quad * 4 + r) * 136 + ct * 16 + m] = (_Float16)acc[ct][r];
            int vr = N - row0; if (vr > 16) vr = 16;
            float4* dst = (float4*)(xw1 + (size_t)row0 * 128);
            for (int i = lane; i < vr * 16; i += 64) {
                int r = i >> 4, q = i & 15;
                dst[r * 16 + q] = *(const float4*)&myO[r * 136 + q * 8];
            }
        }
    }
}

// ---------------------------------------------------------------------------
// FUSED gather1 + gemm2 (4-edge unroll; plain cached loads — NT regressed).
// Epilogue PRE-SCALES xw2 rows by dinv[node]. Per-edge norm from packed
// dinv[] table.
// ---------------------------------------------------------------------------
__global__ __launch_bounds__(256)
void k_g1g2(const __half* __restrict__ xw1, const int* __restrict__ cnt,
            const float* __restrict__ dinv,
            const int* __restrict__ slots, const float* __restrict__ bias,
            const half8* __restrict__ wf2, __half* __restrict__ xw2, int N) {
    __shared__ __align__(16) _Float16 Ht[16 * 136];   // h tile, padded
    __shared__ __align__(16) _Float16 Of[16 * 72];    // xw2 transpose
    __shared__ float dv16[16];                        // dinv per tile row

    const int row0 = blockIdx.x * 16;
    const int local = threadIdx.x >> 4;     // 0..15: node within tile
    const int lane16 = threadIdx.x & 15;    // feature quad: 8 halves
    const int node = row0 + local;

    // ---- phase 1: gather ----
    {
        union { __half2 h2[4]; float4 f; } u;
        float dvn = 0.f;
        if (node < N) {
            int cn = cnt[node];
            int len = cn > CAP ? CAP : cn;
            dvn = dinv[node];
            const int* sl = slots + (size_t)node * CAP;
            float acc[8];
            {
                float4 raw = *(const float4*)(xw1 + (size_t)node * 128 + lane16 * 8);
                const __half2* hp = (const __half2*)&raw;
#pragma unroll
                for (int k = 0; k < 4; ++k) {
                    float2 f = __half22float2(hp[k]);
                    acc[2 * k] = dvn * f.x; acc[2 * k + 1] = dvn * f.y;
                }
            }
            int j = 0;
            for (; j + 3 < len; j += 4) {
                int4 cc = *(const int4*)(sl + j);
                float dv0 = dinv[cc.x];
                float dv1 = dinv[cc.y];
                float dv2 = dinv[cc.z];
                float dv3 = dinv[cc.w];
                float4 raw0 = *(const float4*)(xw1 + (size_t)cc.x * 128 + lane16 * 8);
                float4 raw1 = *(const float4*)(xw1 + (size_t)cc.y * 128 + lane16 * 8);
                float4 raw2 = *(const float4*)(xw1 + (size_t)cc.z * 128 + lane16 * 8);
                float4 raw3 = *(const float4*)(xw1 + (size_t)cc.w * 128 + lane16 * 8);
                const __half2* h0 = (const __half2*)&raw0;
                const __half2* h1 = (const __half2*)&raw1;
                const __half2* h2 = (const __half2*)&raw2;
                const __half2* h3 = (const __half2*)&raw3;
#pragma unroll
                for (int k = 0; k < 4; ++k) {
                    float2 f0 = __half22float2(h0[k]);
                    float2 f1 = __half22float2(h1[k]);
                    float2 f2 = __half22float2(h2[k]);
                    float2 f3 = __half22float2(h3[k]);
                    acc[2 * k]     = fmaf(dv0, f0.x, fmaf(dv1, f1.x,
                                     fmaf(dv2, f2.x, fmaf(dv3, f3.x, acc[2 * k]))));
                    acc[2 * k + 1] = fmaf(dv0, f0.y, fmaf(dv1, f1.y,
                                     fmaf(dv2, f2.y, fmaf(dv3, f3.y, acc[2 * k + 1]))));
                }
            }
            for (; j < len; ++j) {
                int c = sl[j];
                float dv = dinv[c];
                float4 raw = *(const float4*)(xw1 + (size_t)c * 128 + lane16 * 8);
                const __half2* hp = (const __half2*)&raw;
#pragma unroll
                for (int k = 0; k < 4; ++k) {
                    float2 f = __half22float2(hp[k]);
                    acc[2 * k]     = fmaf(dv, f.x, acc[2 * k]);
                    acc[2 * k + 1] = fmaf(dv, f.y, acc[2 * k + 1]);
                }
            }
            float4 b01 = ((const float4*)bias)[lane16 * 2];
            float4 b23 = ((const float4*)bias)[lane16 * 2 + 1];
            float v[8];
            v[0] = b01.x + dvn * acc[0]; v[1] = b01.y + dvn * acc[1];
            v[2] = b01.z + dvn * acc[2]; v[3] = b01.w + dvn * acc[3];
            v[4] = b23.x + dvn * acc[4]; v[5] = b23.y + dvn * acc[5];
            v[6] = b23.z + dvn * acc[6]; v[7] = b23.w + dvn * acc[7];
#pragma unroll
            for (int k = 0; k < 4; ++k)
                u.h2[k] = __floats2half2_rn(fmaxf(v[2 * k], 0.f), fmaxf(v[2 * k + 1], 0.f));
        } else {
            u.f = make_float4(0.f, 0.f, 0.f, 0.f);
        }
        if (lane16 == 0) dv16[local] = dvn;
        *(float4*)(Ht + local * 136 + lane16 * 8) = u.f;
    }
    __syncthreads();

    // ---- phase 2: MFMA h_tile @ W2, wave ct; scale rows by dinv[node] ----
    {
        const int wave = threadIdx.x >> 6, lane = threadIdx.x & 63;
        const int m = lane & 15, quad = lane >> 4;
        f32x4 acc = (f32x4){0.f, 0.f, 0.f, 0.f};
#pragma unroll
        for (int kb = 0; kb < 4; ++kb) {
            half8 a = *(const half8*)(Ht + m * 136 + kb * 32 + quad * 8);
            half8 b = wf2[(wave * 4 + kb) * 64 + lane];
            acc = __builtin_amdgcn_mfma_f32_16x16x32_f16(a, b, acc, 0, 0, 0);
        }
#pragma unroll
        for (int r = 0; r < 4; ++r)
            Of[(quad * 4 + r) * 72 + wave * 16 + m] =
                (_Float16)(acc[r] * dv16[quad * 4 + r]);
    }
    __syncthreads();
    {
        int vr = N - row0; if (vr > 16) vr = 16;
        float4* dst = (float4*)(xw2 + (size_t)row0 * 64);
        for (int i = threadIdx.x; i < vr * 8; i += TPB) {
            int r = i >> 3, q = i & 7;
            dst[r * 8 + q] = *(const float4*)&Of[r * 72 + q * 8];
        }
    }
}

// ---------------------------------------------------------------------------
// Capacity-CSR gather, layer 2 (F=64, fp16 src PRE-SCALED by dinv[src]),
// FUSED bias + self-loop + norm + log_softmax. 8 lanes x 16B per row.
// ---------------------------------------------------------------------------
__global__ void k_gather2_lsm(const __half* __restrict__ xws, const int* __restrict__ cnt,
                              const float* __restrict__ dinv,
                              const int* __restrict__ slots,
                              const float* __restrict__ bias, float* __restrict__ out, int N) {
    long long t = (long long)blockIdx.x * TPB + threadIdx.x;
    int node = (int)(t >> 3);
    int lane = (int)(t & 7);              // 8 features (16B fp16) per lane
    if (node >= N) return;
    int cn = cnt[node];
    int len = cn > CAP ? CAP : cn;
    float dvn = dinv[node];
    const int* sl = slots + (size_t)node * CAP;
    float a[8];
    {
        // self term: stored row is dvn*h2[n]; final *dvn gives dvn^2*h2[n].
        float4 raw = *(const float4*)(xws + (size_t)node * 64 + lane * 8);
        const __half2* hp = (const __half2*)&raw;
#pragma unroll
        for (int k = 0; k < 4; ++k) {
            float2 f = __half22float2(hp[k]);
            a[2 * k] = f.x; a[2 * k + 1] = f.y;
        }
    }
    int j = 0;
    for (; j + 3 < len; j += 4) {
        int4 cc = *(const int4*)(sl + j);
        float4 r0 = *(const float4*)(xws + (size_t)cc.x * 64 + lane * 8);
        float4 r1 = *(const float4*)(xws + (size_t)cc.y * 64 + lane * 8);
        float4 r2 = *(const float4*)(xws + (size_t)cc.z * 64 + lane * 8);
        float4 r3 = *(const float4*)(xws + (size_t)cc.w * 64 + lane * 8);
        const __half2* h0 = (const __half2*)&r0;
        const __half2* h1 = (const __half2*)&r1;
        const __half2* h2 = (const __half2*)&r2;
        const __half2* h3 = (const __half2*)&r3;
#pragma unroll
        for (int k = 0; k < 4; ++k) {
            float2 f0 = __half22float2(h0[k]);
            float2 f1 = __half22float2(h1[k]);
            float2 f2 = __half22float2(h2[k]);
            float2 f3 = __half22float2(h3[k]);
            a[2 * k]     += (f0.x + f1.x) + (f2.x + f3.x);
            a[2 * k + 1] += (f0.y + f1.y) + (f2.y + f3.y);
        }
    }
    for (; j < len; ++j) {
        int c = sl[j];
        float4 raw = *(const float4*)(xws + (size_t)c * 64 + lane * 8);
        const __half2* hp = (const __half2*)&raw;
#pragma unroll
        for (int k = 0; k < 4; ++k) {
            float2 f = __half22float2(hp[k]);
            a[2 * k] += f.x; a[2 * k + 1] += f.y;
        }
    }
    float4 b01 = ((const float4*)bias)[lane * 2];
    float4 b23 = ((const float4*)bias)[lane * 2 + 1];
    float v[8];
    v[0] = b01.x + dvn * a[0]; v[1] = b01.y + dvn * a[1];
    v[2] = b01.z + dvn * a[2]; v[3] = b01.w + dvn * a[3];
    v[4] = b23.x + dvn * a[4]; v[5] = b23.y + dvn * a[5];
    v[6] = b23.z + dvn * a[6]; v[7] = b23.w + dvn * a[7];

    float m = v[0];
#pragma unroll
    for (int k = 1; k < 8; ++k) m = fmaxf(m, v[k]);
#pragma unroll
    for (int off = 1; off < 8; off <<= 1) m = fmaxf(m, __shfl_xor(m, off));
    float s = 0.f;
#pragma unroll
    for (int k = 0; k < 8; ++k) s += expf(v[k] - m);
#pragma unroll
    for (int off = 1; off < 8; off <<= 1) s += __shfl_xor(s, off);
    float ls = m + logf(s);
    float4 o0 = make_float4(v[0] - ls, v[1] - ls, v[2] - ls, v[3] - ls);
    float4 o1 = make_float4(v[4] - ls, v[5] - ls, v[6] - ls, v[7] - ls);
    ((float4*)(out + (size_t)node * 64))[lane * 2]     = o0;
    ((float4*)(out + (size_t)node * 64))[lane * 2 + 1] = o1;
}

// ---------------------------------------------------------------------------
extern "C" void kernel_launch(void* const* d_in, const int* in_sizes, int n_in,
                              void* d_out, int out_size, void* d_ws, size_t ws_size,
                              hipStream_t stream) {
    const float* x  = (const float*)d_in[0];
    const void*  ei = d_in[1];
    const float* W1 = (const float*)d_in[2];
    const float* b1 = (const float*)d_in[3];
    const float* W2 = (const float*)d_in[4];
    const float* b2 = (const float*)d_in[5];
    float* out = (float*)d_out;

    const int N = in_sizes[0] / 128;   // 100000  (must be < 2^17 for packing)
    const int E = in_sizes[1] / 2;     // 1600000

    const int nFW  = (N + FWROWS - 1) >> FWSHIFT;             // 196
    const int nDec = (E + DEC_EDGES - 1) / DEC_EDGES;         // 196
    const int nGemm = 512;

    char* base = (char*)d_ws;
    size_t off = 0;
    auto alloc = [&](size_t bytes) { char* p = base + off; off = (off + bytes + 255) & ~(size_t)255; return p; };
    int*      cnt    = (int*)alloc((size_t)N * sizeof(int));
    float*    dinv   = (float*)alloc((size_t)N * sizeof(float));
    _Float16* wf2    = (_Float16*)alloc(128 * 64 * sizeof(_Float16));
    int*      bbase  = (int*)alloc((size_t)nFW * nDec * sizeof(int));
    int*      bcnt   = (int*)alloc((size_t)nFW * nDec * sizeof(int));
    int*      bpack  = (int*)alloc((size_t)nDec * DEC_EDGES * sizeof(int)); // 6.4MB dense
    int*      slots  = (int*)alloc((size_t)N * CAP * sizeof(int));
    __half*   xw1    = (__half*)alloc((size_t)N * 128 * sizeof(__half));
    __half*   xw2    = (__half*)alloc((size_t)N * 64 * sizeof(__half));
    (void)ws_size;

    const int nodeTiles = (N + 15) / 16;

    k_setup<<<8 + nDec, TPB, 0, stream>>>(ei, E, N, W2, wf2, bpack, bbase,
                                          bcnt, nDec, nFW);

    k_mega<<<nFW + nGemm, TPB, 0, stream>>>(bpack, bbase, bcnt, nDec, N, cnt,
                                            dinv, slots, x, W1, xw1, nFW, nGemm);

    k_g1g2<<<nodeTiles, TPB, 0, stream>>>(xw1, cnt, dinv, slots, b1,
                                          (const half8*)wf2, xw2, N);

    {
        long long t = (long long)N * 8;
        k_gather2_lsm<<<(int)((t + TPB - 1) / TPB), TPB, 0, stream>>>(xw2, cnt, dinv, slots, b2, out, N);
    }
}